// Round 4
// baseline (339.147 us; speedup 1.0000x reference)
//
#include <hip/hip_runtime.h>
#include <math.h>

// DIAGNOSTIC ROUND: exact R2 structure (best measured: 307 us), launched
// TWICE with scale/2 (identical output, atomics accumulate). The dur_us
// delta vs R2 measures one kernel dispatch directly, since rocprof top-5
// only shows the harness's 120us ws-poison fills and our kernel is <118us.
//
// Structure: one block per batch b (512 blocks x 256 thr), all S in-block,
// samples staged to LDS via float4, S-unrolled inner loop (12 gathers in
// flight), wave-shuffle + LDS reduce, 2 scaled atomics per block.

#define NGRID3     32768            // 32^3
#define GRID_MIN_F (-0.484375f)     // -0.5 + 0.5/32
#define NTHREADS   256

__device__ __forceinline__ float point_loss(float x, float y, float z,
                                            const float* __restrict__ vol,
                                            const float* __restrict__ cp)
{
    float fx = fminf(fmaxf((x - GRID_MIN_F) * 32.0f, 0.0f), 31.0f);
    float fy = fminf(fmaxf((y - GRID_MIN_F) * 32.0f, 0.0f), 31.0f);
    float fz = fminf(fmaxf((z - GRID_MIN_F) * 32.0f, 0.0f), 31.0f);
    int lin = ((int)rintf(fx)) * 1024 + ((int)rintf(fy)) * 32 + (int)rintf(fz);

    float m  = 1.0f - vol[lin];
    float dx = (x - cp[lin * 3 + 0]) * m;
    float dy = (y - cp[lin * 3 + 1]) * m;
    float dz = (z - cp[lin * 3 + 2]) * m;
    return sqrtf(fmaxf(dx * dx + dy * dy + dz * dz, 1e-30f));
}

template <int S>
__global__ __launch_bounds__(NTHREADS) void symloss_fused(
    const float* __restrict__ planes,   // (S,B,4)
    const float* __restrict__ quats,    // (S,B,4)
    const float* __restrict__ cps,      // (B, 32768*3)
    const float* __restrict__ samples,  // (B,N,3)
    const float* __restrict__ volume,   // (B, 32768)
    float* __restrict__ out,            // 2 floats
    int B, int N, float scale)
{
    const int b = blockIdx.x;
    const float* __restrict__ vol = volume + (size_t)b * NGRID3;
    const float* __restrict__ cp  = cps    + (size_t)b * NGRID3 * 3;

    extern __shared__ float spts[];     // N*3 floats
    {
        const float* sp = samples + (size_t)b * N * 3;
        const int n4 = (N * 3) / 4;
        const float4* src = (const float4*)sp;
        float4* dst = (float4*)spts;
        for (int i = threadIdx.x; i < n4; i += NTHREADS) dst[i] = src[i];
        for (int i = n4 * 4 + threadIdx.x; i < N * 3; i += NTHREADS) spts[i] = sp[i];
    }

    float plx[S], ply[S], plz[S], plw[S], inv_n2[S];
    float qw[S], qx[S], qy[S], qz[S], w2mu[S];
#pragma unroll
    for (int s = 0; s < S; ++s) {
        float4 pl = ((const float4*)planes)[(size_t)s * B + b];
        float4 q  = ((const float4*)quats )[(size_t)s * B + b];
        plx[s] = pl.x; ply[s] = pl.y; plz[s] = pl.z; plw[s] = pl.w;
        inv_n2[s] = 1.0f / (pl.x * pl.x + pl.y * pl.y + pl.z * pl.z + 1e-8f);
        qw[s] = q.x; qx[s] = q.y; qy[s] = q.z; qz[s] = q.w;
        w2mu[s] = q.x * q.x - (q.y * q.y + q.z * q.z + q.w * q.w);
    }

    __syncthreads();

    float sum_p = 0.0f, sum_q = 0.0f;
    for (int n = threadIdx.x; n < N; n += NTHREADS) {
        const float px = spts[n * 3 + 0];
        const float py = spts[n * 3 + 1];
        const float pz = spts[n * 3 + 2];
#pragma unroll
        for (int s = 0; s < S; ++s) {
            float f = 2.0f * (px * plx[s] + py * ply[s] + pz * plz[s] + plw[s]) * inv_n2[s];
            sum_p += point_loss(px - f * plx[s], py - f * ply[s], pz - f * plz[s], vol, cp);

            float udp = qx[s] * px + qy[s] * py + qz[s] * pz;
            float cx  = qy[s] * pz - qz[s] * py;
            float cy  = qz[s] * px - qx[s] * pz;
            float cz  = qx[s] * py - qy[s] * px;
            sum_q += point_loss(w2mu[s] * px + 2.0f * (udp * qx[s] + qw[s] * cx),
                                w2mu[s] * py + 2.0f * (udp * qy[s] + qw[s] * cy),
                                w2mu[s] * pz + 2.0f * (udp * qz[s] + qw[s] * cz),
                                vol, cp);
        }
    }

    for (int off = 32; off > 0; off >>= 1) {
        sum_p += __shfl_down(sum_p, off);
        sum_q += __shfl_down(sum_q, off);
    }
    __shared__ float red[NTHREADS / 64][2];
    const int lane = threadIdx.x & 63;
    const int wid  = threadIdx.x >> 6;
    if (lane == 0) { red[wid][0] = sum_p; red[wid][1] = sum_q; }
    __syncthreads();

    if (threadIdx.x == 0) {
        float tp = 0.0f, tq = 0.0f;
        for (int w = 0; w < NTHREADS / 64; ++w) { tp += red[w][0]; tq += red[w][1]; }
        atomicAdd(&out[0], tp * scale);
        atomicAdd(&out[1], tq * scale);
    }
}

template <int S>
static void launch_once(const float* planes, const float* quats, const float* cps,
                        const float* samples, const float* volume, float* out,
                        int B, int N, float scale, size_t lds, hipStream_t stream)
{
    symloss_fused<S><<<B, NTHREADS, lds, stream>>>(planes, quats, cps, samples,
                                                   volume, out, B, N, scale);
}

extern "C" void kernel_launch(void* const* d_in, const int* in_sizes, int n_in,
                              void* d_out, int out_size, void* d_ws, size_t ws_size,
                              hipStream_t stream)
{
    const float* planes  = (const float*)d_in[0];
    const float* quats   = (const float*)d_in[1];
    const float* cps     = (const float*)d_in[2];
    const float* samples = (const float*)d_in[3];
    const float* volume  = (const float*)d_in[4];
    float* out = (float*)d_out;

    const int B = in_sizes[4] / NGRID3;     // 512
    const int S = in_sizes[0] / (B * 4);    // 3
    const int N = in_sizes[3] / (B * 3);    // 1000
    const size_t lds = (size_t)N * 3 * sizeof(float);

    hipMemsetAsync(d_out, 0, 2 * sizeof(float), stream);

    // TWO identical launches, each with half the scale: output identical,
    // dur_us delta vs single-launch round (307us) == one kernel's cost.
    const int REP = 2;
    const float scale = 1.0f / (float)(S * B * REP);

    for (int r = 0; r < REP; ++r) {
        switch (S) {
        case 1: launch_once<1>(planes, quats, cps, samples, volume, out, B, N, scale, lds, stream); break;
        case 2: launch_once<2>(planes, quats, cps, samples, volume, out, B, N, scale, lds, stream); break;
        case 3: launch_once<3>(planes, quats, cps, samples, volume, out, B, N, scale, lds, stream); break;
        case 4: launch_once<4>(planes, quats, cps, samples, volume, out, B, N, scale, lds, stream); break;
        default:
            for (int s = 0; s < S; ++s)
                launch_once<1>(planes + (size_t)s * B * 4, quats + (size_t)s * B * 4,
                               cps, samples, volume, out, B, N, scale, lds, stream);
            break;
        }
    }
}

// Round 5
// 309.707 us; speedup vs baseline: 1.0951x; 1.0951x over previous
//
#include <hip/hip_runtime.h>
#include <math.h>

// R5: R2 structure (best: 307us, kernel ~32us measured via R4 double-launch)
// + CORNER CACHE. The quat path rotates by an UNNORMALIZED quaternion
// (scales points by |q|^2, E~4), so most rotated points clamp in all three
// coords -> one of 8 corner voxels; plane path ~23% corners. Corner
// (mask, cp) depend only on b: load the 8 corners into LDS once per block,
// and corner lanes skip both scattered gathers (cuts L1 divergent
// transactions ~2x; compulsory HBM unchanged).

#define NGRID3     32768            // 32^3
#define GRID_MIN_F (-0.484375f)     // -0.5 + 0.5/32
#define NTHREADS   256

struct Corner { float m, cx, cy, cz; };

__device__ __forceinline__ float point_loss(float x, float y, float z,
                                            const float* __restrict__ vol,
                                            const float* __restrict__ cp,
                                            const Corner* __restrict__ corners)
{
    // jnp: clip to [0,31] then round (nearest-even)
    float fx = fminf(fmaxf((x - GRID_MIN_F) * 32.0f, 0.0f), 31.0f);
    float fy = fminf(fmaxf((y - GRID_MIN_F) * 32.0f, 0.0f), 31.0f);
    float fz = fminf(fmaxf((z - GRID_MIN_F) * 32.0f, 0.0f), 31.0f);
    int ix = (int)rintf(fx), iy = (int)rintf(fy), iz = (int)rintf(fz);

    float m, cx_, cy_, cz_;
    bool corner = ((ix == 0) | (ix == 31)) & ((iy == 0) | (iy == 31))
                & ((iz == 0) | (iz == 31));
    if (corner) {
        // corner id from parity: 0->0, 31->1 per axis
        const Corner c = corners[((ix & 1) << 2) | ((iy & 1) << 1) | (iz & 1)];
        m = c.m; cx_ = c.cx; cy_ = c.cy; cz_ = c.cz;
    } else {
        int lin = ix * 1024 + iy * 32 + iz;
        m   = 1.0f - vol[lin];
        cx_ = cp[lin * 3 + 0];
        cy_ = cp[lin * 3 + 1];
        cz_ = cp[lin * 3 + 2];
    }
    float dx = (x - cx_) * m;
    float dy = (y - cy_) * m;
    float dz = (z - cz_) * m;
    return sqrtf(fmaxf(dx * dx + dy * dy + dz * dz, 1e-30f));
}

template <int S>
__global__ __launch_bounds__(NTHREADS) void symloss_fused(
    const float* __restrict__ planes,   // (S,B,4)
    const float* __restrict__ quats,    // (S,B,4)
    const float* __restrict__ cps,      // (B, 32768*3)
    const float* __restrict__ samples,  // (B,N,3)
    const float* __restrict__ volume,   // (B, 32768)
    float* __restrict__ out,            // 2 floats
    int B, int N, float scale)
{
    const int b = blockIdx.x;
    const float* __restrict__ vol = volume + (size_t)b * NGRID3;
    const float* __restrict__ cp  = cps    + (size_t)b * NGRID3 * 3;

    __shared__ Corner corners[8];
    extern __shared__ float spts[];     // N*3 floats

    // stage samples (coalesced float4)
    {
        const float* sp = samples + (size_t)b * N * 3;
        const int n4 = (N * 3) / 4;
        const float4* src = (const float4*)sp;
        float4* dst = (float4*)spts;
        for (int i = threadIdx.x; i < n4; i += NTHREADS) dst[i] = src[i];
        for (int i = n4 * 4 + threadIdx.x; i < N * 3; i += NTHREADS) spts[i] = sp[i];
    }
    // stage the 8 corner voxels: id bit2=x, bit1=y, bit0=z; 0->idx 0, 1->idx 31
    if (threadIdx.x < 8) {
        const int ix = (threadIdx.x & 4) ? 31 : 0;
        const int iy = (threadIdx.x & 2) ? 31 : 0;
        const int iz = (threadIdx.x & 1) ? 31 : 0;
        const int lin = ix * 1024 + iy * 32 + iz;
        Corner c;
        c.m  = 1.0f - vol[lin];
        c.cx = cp[lin * 3 + 0];
        c.cy = cp[lin * 3 + 1];
        c.cz = cp[lin * 3 + 2];
        corners[threadIdx.x] = c;
    }

    float plx[S], ply[S], plz[S], plw[S], inv_n2[S];
    float qw[S], qx[S], qy[S], qz[S], w2mu[S];
#pragma unroll
    for (int s = 0; s < S; ++s) {
        float4 pl = ((const float4*)planes)[(size_t)s * B + b];
        float4 q  = ((const float4*)quats )[(size_t)s * B + b];
        plx[s] = pl.x; ply[s] = pl.y; plz[s] = pl.z; plw[s] = pl.w;
        inv_n2[s] = 1.0f / (pl.x * pl.x + pl.y * pl.y + pl.z * pl.z + 1e-8f);
        qw[s] = q.x; qx[s] = q.y; qy[s] = q.z; qz[s] = q.w;
        w2mu[s] = q.x * q.x - (q.y * q.y + q.z * q.z + q.w * q.w);
    }

    __syncthreads();

    float sum_p = 0.0f, sum_q = 0.0f;
    for (int n = threadIdx.x; n < N; n += NTHREADS) {
        const float px = spts[n * 3 + 0];
        const float py = spts[n * 3 + 1];
        const float pz = spts[n * 3 + 2];
#pragma unroll
        for (int s = 0; s < S; ++s) {
            // plane reflection
            float f = 2.0f * (px * plx[s] + py * ply[s] + pz * plz[s] + plw[s]) * inv_n2[s];
            sum_p += point_loss(px - f * plx[s], py - f * ply[s], pz - f * plz[s],
                                vol, cp, corners);

            // quaternion rotate (unnormalized): (w^2-|u|^2)p + 2(u.p)u + 2w(u x p)
            float udp = qx[s] * px + qy[s] * py + qz[s] * pz;
            float cx  = qy[s] * pz - qz[s] * py;
            float cy  = qz[s] * px - qx[s] * pz;
            float cz  = qx[s] * py - qy[s] * px;
            sum_q += point_loss(w2mu[s] * px + 2.0f * (udp * qx[s] + qw[s] * cx),
                                w2mu[s] * py + 2.0f * (udp * qy[s] + qw[s] * cy),
                                w2mu[s] * pz + 2.0f * (udp * qz[s] + qw[s] * cz),
                                vol, cp, corners);
        }
    }

    for (int off = 32; off > 0; off >>= 1) {
        sum_p += __shfl_down(sum_p, off);
        sum_q += __shfl_down(sum_q, off);
    }
    __shared__ float red[NTHREADS / 64][2];
    const int lane = threadIdx.x & 63;
    const int wid  = threadIdx.x >> 6;
    if (lane == 0) { red[wid][0] = sum_p; red[wid][1] = sum_q; }
    __syncthreads();

    if (threadIdx.x == 0) {
        float tp = 0.0f, tq = 0.0f;
        for (int w = 0; w < NTHREADS / 64; ++w) { tp += red[w][0]; tq += red[w][1]; }
        atomicAdd(&out[0], tp * scale);
        atomicAdd(&out[1], tq * scale);
    }
}

extern "C" void kernel_launch(void* const* d_in, const int* in_sizes, int n_in,
                              void* d_out, int out_size, void* d_ws, size_t ws_size,
                              hipStream_t stream)
{
    const float* planes  = (const float*)d_in[0];
    const float* quats   = (const float*)d_in[1];
    const float* cps     = (const float*)d_in[2];
    const float* samples = (const float*)d_in[3];
    const float* volume  = (const float*)d_in[4];
    float* out = (float*)d_out;

    const int B = in_sizes[4] / NGRID3;     // 512
    const int S = in_sizes[0] / (B * 4);    // 3
    const int N = in_sizes[3] / (B * 3);    // 1000
    const float scale = 1.0f / (float)(S * B);
    const size_t lds = (size_t)N * 3 * sizeof(float);

    hipMemsetAsync(d_out, 0, 2 * sizeof(float), stream);

    switch (S) {
    case 1: symloss_fused<1><<<B, NTHREADS, lds, stream>>>(planes, quats, cps, samples, volume, out, B, N, scale); break;
    case 2: symloss_fused<2><<<B, NTHREADS, lds, stream>>>(planes, quats, cps, samples, volume, out, B, N, scale); break;
    case 3: symloss_fused<3><<<B, NTHREADS, lds, stream>>>(planes, quats, cps, samples, volume, out, B, N, scale); break;
    case 4: symloss_fused<4><<<B, NTHREADS, lds, stream>>>(planes, quats, cps, samples, volume, out, B, N, scale); break;
    default:
        for (int s = 0; s < S; ++s)
            symloss_fused<1><<<B, NTHREADS, lds, stream>>>(planes + (size_t)s * B * 4,
                                                           quats  + (size_t)s * B * 4,
                                                           cps, samples, volume, out, B, N, scale);
        break;
    }
}